// Round 7
// baseline (34.065 us; speedup 1.0000x reference)
//
#include <hip/hip_runtime.h>

#define GRIDD  76                 // grid dim (H = W)
#define NROWS  255                // anchors(3) * attrs(85)
#define GG     (GRIDD * GRIDD)    // 5776
#define WR     16                 // rem rows per wave
#define WQ     (WR * 19)          // 304 float4 quads per wave
#define WDW    (WR * GRIDD)       // 1216 floats per wave LDS region

typedef __attribute__((address_space(3))) unsigned lds_u32;
typedef __attribute__((address_space(1))) unsigned glb_u32;

__device__ __forceinline__ void gll16(const float* g, float* l) {
    // async global->LDS, 16B/lane; LDS dest = wave-uniform base + lane*16
    __builtin_amdgcn_global_load_lds((const glb_u32*)g, (lds_u32*)l, 16, 0, 0);
}

__global__ __launch_bounds__(512, 8) void yolo_head_kernel(
    const float* __restrict__ x, const int* __restrict__ dimp,
    float* __restrict__ out)
{
    __shared__ float buf[8 * WDW];            // 38912 B -> 4 blocks/CU
    // XCD-bijective swizzle (2432 = 8*304): both halves of a rem column and
    // neighboring h share one XCD L2 -> seam/segment lines merge before HBM.
    const unsigned lb    = (blockIdx.x & 7u) * 304u + (blockIdx.x >> 3);
    const unsigned b     = lb / 152u;
    const unsigned hr    = lb - b * 152u;
    const unsigned h     = hr >> 1;
    const unsigned rbase = (hr & 1u) * 127u;  // unit rows rbase..rbase+127
    const unsigned t     = threadIdx.x;
    const unsigned W     = t >> 6;
    const unsigned lane  = t & 63u;
    const float stride   = (float)(*dimp / GRIDD);   // 608/76 = 8
    const float mB       = -0.1f * stride;

    // ---- phase 1: wave stages its OWN 16 rows x 76 w (no block barrier) ----
    float* wbuf = buf + W * WDW;              // linear [16][76] slab
    const unsigned wr0 = rbase + W * WR;      // wave's first rem row
    const float* __restrict__ src = x + (size_t)(b * NROWS + wr0) * GG + h * GRIDD;
    #pragma unroll
    for (unsigned k = 0; k < 5u; ++k) {
        unsigned i = k * 64u + lane;          // quad index 0..303
        if (i < WQ) {                         // k=4: lanes 0..47
            unsigned row = i / 19u;
            unsigned qc  = i - row * 19u;
            gll16(src + (size_t)row * GG + (qc << 2), wbuf + k * 256u);
        }
    }
    // wave-private sync: wait on this wave's own loads only
    asm volatile("s_waitcnt vmcnt(0)" ::: "memory");

    // ---- phase 2: lane = (r = lane&15, qj = lane>>4 + 4j); all attr logic
    //      is lane-fixed -> hoisted out of the loop ----
    const unsigned r    = lane & 15u;
    const unsigned rem  = wr0 + r;            // 0..254
    const unsigned a    = (rem >= 170u) ? 2u : ((rem >= 85u) ? 1u : 0u);
    const unsigned attr = rem - a * 85u;
    const bool  wh  = (attr == 2u) | (attr == 3u);
    const bool  isx = (attr == 0u);
    float anc = 0.f;
    if (attr == 2u) anc = (a == 0u) ? 12.f : ((a == 1u) ? 19.f : 40.f);
    if (attr == 3u) anc = (a == 0u) ? 16.f : ((a == 1u) ? 36.f : 28.f);
    const float sgn = wh ? 1.f : -1.f;
    const float A   = (attr < 2u) ? 1.2f * stride : 1.f;
    const float B0  = (attr == 1u) ? ((float)h * stride + mB) : 0.f;

    const float* lr = wbuf + r * GRIDD;       // quad-bank (3r+qj)%8: uniform, ~free
    float* __restrict__ dst = out + (size_t)(b * GRIDD + h) * (GRIDD * NROWS) + rem;

    #pragma unroll
    for (unsigned j = 0; j < 5u; ++j) {
        const unsigned qj = (lane >> 4) + (j << 2);    // 0..18
        if (qj < 19u) {                                // j=4: lanes 0..47
            const float4 vv = *reinterpret_cast<const float4*>(lr + (qj << 2));
            #pragma unroll
            for (unsigned i = 0; i < 4u; ++i) {
                const float v = (i == 0) ? vv.x : (i == 1) ? vv.y : (i == 2) ? vv.z : vv.w;
                const unsigned u = (qj << 2) + i;
                const float e   = __expf(sgn * v);
                const float sig = __builtin_amdgcn_rcpf(1.0f + e);
                const float Bi  = isx ? fmaf((float)u, stride, mB) : B0;
                const float o   = wh ? e * anc : fmaf(sig, A, Bi);
                dst[(size_t)u * NROWS] = o;   // 16-rem 64B segments, L2-merged
            }
        }
    }
}

extern "C" void kernel_launch(void* const* d_in, const int* in_sizes, int n_in,
                              void* d_out, int out_size, void* d_ws, size_t ws_size,
                              hipStream_t stream) {
    const float* x  = (const float*)d_in[0];
    const int* dimp = (const int*)d_in[1];
    float* out      = (float*)d_out;
    const int B = in_sizes[0] / (NROWS * GG);   // 16
    yolo_head_kernel<<<B * GRIDD * 2, 512, 0, stream>>>(x, dimp, out);
}